// Round 21
// baseline (69.794 us; speedup 1.0000x reference)
//
#include <hip/hip_runtime.h>
#include <hip/hip_bf16.h>

// FConv2d, round 21 (resubmit; r20 acquisition timeout — no bench data):
// traffic-term attack from the r16/r18 ledger.
// Single-shot model (validated: 31.5 halo-fetch + 16.8 out + ~32 poison-
// dirty L2 writeback at ~3.5TB/s = 23us = measured):
//  (1) 2 output rows/block (grid 256, 1 block/CU): halo 3x -> 2x,
//      x requests 31.5 -> 21 MB. Staging = r13-VERIFIED 4-row code.
//  (2) nontemporal x loads: discourage L2 allocation -> dodge the
//      poison-dirty eviction writebacks (halo re-reads never hit L2
//      anyway: warm FETCH stayed 34MB in r18).
//  (3) keep nt LDS-staged epilogue; 2-row tile = 64KB, union over
//      xs+wf (both dead after compute; barriers order the phases).
// Compute math IDENTICAL to verified lineage (absmax 0.015625):
// out[b,d*16+n,r,s] = sum 0.5W[n,c2,2-u,2-v]*(xa+xb)[r+u,s+v];
// d=0/8: xa==xb -> acc doubled; mirror d'=16-d same values.
// Waves = 8 d-groups {0,8},{4},{2},{6},{1},{5},{3},{7}; each does
// (2 rows x 2 col-halves) -> 72 MFMA/wave, balanced.

typedef __attribute__((ext_vector_type(8))) short short8;
typedef __attribute__((ext_vector_type(4))) float floatx4;

#define NT 512
#define LCH 168                 // padded channel-slot dim (160 used)
#define SROWS 34                // cols per staged row (32..33 zero apron)
#define XSROW (SROWS * LCH)     // 5712 shorts per staged row

template<int D, bool DUP>
__device__ __forceinline__ floatx4 compute_d_acc(const char* basep, const short8 af[9]) {
    floatx4 a0 = {0.f,0.f,0.f,0.f}, a1 = {0.f,0.f,0.f,0.f};
    floatx4 b0 = {0.f,0.f,0.f,0.f}, b1 = {0.f,0.f,0.f,0.f};
#pragma unroll
    for (int u = 0; u < 3; ++u)
#pragma unroll
        for (int v = 0; v < 3; ++v) {
            const int t = u * 3 + v;
            const short8 ba = *(const short8*)(basep +
                ((u * SROWS + v) * LCH + 8 * (8 + D)) * 2);
            if (t & 1) a1 = __builtin_amdgcn_mfma_f32_16x16x32_bf16(af[t], ba, a1, 0, 0, 0);
            else       a0 = __builtin_amdgcn_mfma_f32_16x16x32_bf16(af[t], ba, a0, 0, 0, 0);
            if (!DUP) {
                const short8 bb = *(const short8*)(basep +
                    ((u * SROWS + v) * LCH + 8 * (8 - D)) * 2);
                if (t & 1) b1 = __builtin_amdgcn_mfma_f32_16x16x32_bf16(af[t], bb, b1, 0, 0, 0);
                else       b0 = __builtin_amdgcn_mfma_f32_16x16x32_bf16(af[t], bb, b0, 0, 0, 0);
            }
        }
    floatx4 acc = a0 + a1;
    if (DUP) acc = acc + acc;          // xa==xb: 2*(0.5W*xa) = W*xa, bit-identical
    else     acc = acc + (b0 + b1);
    return acc;
}

__global__ __launch_bounds__(NT, 2)
void fconv_mfma(const float* __restrict__ x,
                const float* __restrict__ wgt,
                float* __restrict__ out) {
    // union: phase A = xs (45,696B @0) + wf (11,520B @46,080);
    //        phase B = ot (65,536B, aliases both). Barriers order phases.
    __shared__ __align__(16) char smem[65536];
    short* xs = (short*)smem;
    short* wf = (short*)(smem + 46080);
    float* ot = (float*)smem;

    const int bid = blockIdx.x;    // 0..255
    const int b   = (bid & 7) + (((bid >> 3) & 1) << 3);   // batch->XCD swizzle
    const int r0  = (bid >> 4) * 2;                        // 0,2,..,30
    const int tid  = threadIdx.x;
    const int lane = tid & 63;
    const int wv   = tid >> 6;

    // ---- weights -> LDS: wf[(8-k)*640 + n*40 + oct*8 + (7-j)] = 0.5*W[n][8oct+j][k]
    {
        const int nn = tid >> 5;        // 0..15
        const int c2 = tid & 31;
        const float* wb = wgt + (size_t)(nn * 32 + c2) * 9;
        const int pos = nn * 40 + (c2 & 24) + (7 - (c2 & 7));
#pragma unroll
        for (int k = 0; k < 9; ++k) {
            __hip_bfloat16 h = __float2bfloat16(0.5f * wb[k]);
            wf[(8 - k) * 640 + pos] = __builtin_bit_cast(short, h);
        }
    }

    // ---- stage raw x rows r0..r0+3 (r13-verified): 2560 tasks, 5/thread ----
    const float* xb_base = x + ((size_t)b << 17);
#pragma unroll
    for (int it = 0; it < 5; ++it) {
        const int idx  = wv * 320 + it * 64 + lane;   // 0..2559
        const int col  = idx & 31;
        const int rest = idx >> 5;                    // 0..79
        const int lrow = rest & 3;
        const int oL   = rest >> 2;                   // 0..19
        const int grow = r0 + lrow;
        short8 g;
        if (grow < 32) {
            float v[8];
#pragma unroll
            for (int j = 0; j < 8; ++j) {
                const int m = (oL * 8 + j - 95) & 127;   // channel (L-95) mod 128
                v[j] = __builtin_nontemporal_load(
                    xb_base + ((m << 5) + grow) * 32 + col);
            }
            union { __hip_bfloat162 h2[4]; short8 s8; } u;
#pragma unroll
            for (int p = 0; p < 4; ++p)
                u.h2[p] = __float22bfloat162_rn(make_float2(v[2 * p], v[2 * p + 1]));
            g = u.s8;
        } else {
            g = short8{0, 0, 0, 0, 0, 0, 0, 0};
        }
        *(short8*)&xs[(lrow * SROWS + col) * LCH + oL * 8] = g;
    }
    // s-apron (col 32,33) zeros: 4 lrow * 2 col * 20 oL = 160 granules
    if (tid < 160) {
        const int oL   = tid % 20;
        const int rem  = tid / 20;       // 0..7
        const int lrow = rem >> 1;
        const int col  = 32 + (rem & 1);
        short8 z = {0, 0, 0, 0, 0, 0, 0, 0};
        *(short8*)&xs[(lrow * SROWS + col) * LCH + oL * 8] = z;
    }

    __syncthreads();

    // ---- A fragments: 9 ds_read_b128 ----
    const int n = lane & 15;      // filter row / D col lane
    const int q = lane >> 4;      // k-octet
    short8 af[9];
#pragma unroll
    for (int t = 0; t < 9; ++t)
        af[t] = *(const short8*)&wf[t * 640 + n * 40 + q * 8];

    // ---- compute into regs: wave = one d-group, 2 rows x 2 col-halves ----
    const char* xb0 = (const char*)xs;
#define BP(lr, s0) (xb0 + (((lr) * SROWS + (s0) + n) * LCH + 8 * (3 - q)) * 2)
    floatx4 rA[4];                 // d-slot A: (lr,i) = (0,0),(0,1),(1,0),(1,1)
    floatx4 rB[4];                 // d-slot B (wv0 only: d=8)
    int dA, dB = -1;
    switch (wv) {
    case 0:
        rA[0] = compute_d_acc<0, true >(BP(0, 0), af);
        rA[1] = compute_d_acc<0, true >(BP(0, 16), af);
        rA[2] = compute_d_acc<0, true >(BP(1, 0), af);
        rA[3] = compute_d_acc<0, true >(BP(1, 16), af);
        rB[0] = compute_d_acc<8, true >(BP(0, 0), af);
        rB[1] = compute_d_acc<8, true >(BP(0, 16), af);
        rB[2] = compute_d_acc<8, true >(BP(1, 0), af);
        rB[3] = compute_d_acc<8, true >(BP(1, 16), af);
        dA = 0; dB = 8; break;
    case 1:
        rA[0] = compute_d_acc<4, false>(BP(0, 0), af);
        rA[1] = compute_d_acc<4, false>(BP(0, 16), af);
        rA[2] = compute_d_acc<4, false>(BP(1, 0), af);
        rA[3] = compute_d_acc<4, false>(BP(1, 16), af);
        dA = 4; break;
    case 2:
        rA[0] = compute_d_acc<2, false>(BP(0, 0), af);
        rA[1] = compute_d_acc<2, false>(BP(0, 16), af);
        rA[2] = compute_d_acc<2, false>(BP(1, 0), af);
        rA[3] = compute_d_acc<2, false>(BP(1, 16), af);
        dA = 2; break;
    case 3:
        rA[0] = compute_d_acc<6, false>(BP(0, 0), af);
        rA[1] = compute_d_acc<6, false>(BP(0, 16), af);
        rA[2] = compute_d_acc<6, false>(BP(1, 0), af);
        rA[3] = compute_d_acc<6, false>(BP(1, 16), af);
        dA = 6; break;
    case 4:
        rA[0] = compute_d_acc<1, false>(BP(0, 0), af);
        rA[1] = compute_d_acc<1, false>(BP(0, 16), af);
        rA[2] = compute_d_acc<1, false>(BP(1, 0), af);
        rA[3] = compute_d_acc<1, false>(BP(1, 16), af);
        dA = 1; break;
    case 5:
        rA[0] = compute_d_acc<5, false>(BP(0, 0), af);
        rA[1] = compute_d_acc<5, false>(BP(0, 16), af);
        rA[2] = compute_d_acc<5, false>(BP(1, 0), af);
        rA[3] = compute_d_acc<5, false>(BP(1, 16), af);
        dA = 5; break;
    case 6:
        rA[0] = compute_d_acc<3, false>(BP(0, 0), af);
        rA[1] = compute_d_acc<3, false>(BP(0, 16), af);
        rA[2] = compute_d_acc<3, false>(BP(1, 0), af);
        rA[3] = compute_d_acc<3, false>(BP(1, 16), af);
        dA = 3; break;
    default:
        rA[0] = compute_d_acc<7, false>(BP(0, 0), af);
        rA[1] = compute_d_acc<7, false>(BP(0, 16), af);
        rA[2] = compute_d_acc<7, false>(BP(1, 0), af);
        rA[3] = compute_d_acc<7, false>(BP(1, 16), af);
        dA = 7; break;
    }
#undef BP

    __syncthreads();   // all xs/wf reads done; safe to alias ot over smem

    // ---- out tile -> LDS: ot[(ch*2 + lr)*32 + s], ch = d*16+q*4+reg ----
    {
        const int chb = q * 4;
#pragma unroll
        for (int sub = 0; sub < 4; ++sub) {        // (lr, i)
            const int lr = sub >> 1;
            const int s  = ((sub & 1) << 4) + n;
#pragma unroll
            for (int reg = 0; reg < 4; ++reg) {
                const float vA = rA[sub][reg];
                ot[((dA * 16 + chb + reg) * 2 + lr) * 32 + s] = vA;
                if (dA >= 1 && dA <= 7)
                    ot[(((16 - dA) * 16 + chb + reg) * 2 + lr) * 32 + s] = vA;
                if (dB >= 0)
                    ot[((dB * 16 + chb + reg) * 2 + lr) * 32 + s] = rB[sub][reg];
            }
        }
    }

    __syncthreads();

    // ---- stream out: 8x (ds_read_b128 + nt floatx4 store); per wave-instr
    //      1KB contiguous global span; every 128-B line single-visit ----
    float* ob = out + ((size_t)b << 18) + r0 * 32;   // b*256*1024 + r0*32
#pragma unroll
    for (int k = 0; k < 8; ++k) {
        const int idx = k * 2048 + tid * 4;          // 0..16380, exact cover
        const floatx4 v = *(const floatx4*)&ot[idx];
        const int ch = idx >> 6;
        const int rs = idx & 63;                     // rr*32 + s
        __builtin_nontemporal_store(v, (floatx4*)(ob + ch * 1024 + rs));
    }
}

extern "C" void kernel_launch(void* const* d_in, const int* in_sizes, int n_in,
                              void* d_out, int out_size, void* d_ws, size_t ws_size,
                              hipStream_t stream) {
    const float* x   = (const float*)d_in[0];   // (16,128,32,32) fp32
    const float* wgt = (const float*)d_in[1];   // (16,32,3,3)   fp32
    float* out = (float*)d_out;                 // (16,256,32,32) fp32
    (void)in_sizes; (void)n_in; (void)out_size; (void)d_ws; (void)ws_size;

    fconv_mfma<<<dim3(256), dim3(NT), 0, stream>>>(x, wgt, out);
}